// Round 18
// baseline (86.835 us; speedup 1.0000x reference)
//
#include <hip/hip_runtime.h>
#include <math.h>

#define NNODES 50000
#define NEDGES 800000
#define NBASIS 10
#define NT 2048
#define RCUT 3.0f
#define CAP 24          // padded slots/node; P(Poisson(3.6) >= 24) ~ 2e-15

// ws layout (bytes):
//   tabP   @ 0x000000 : float[(NT-1)*256]   (~2 MB, interleaved pair table)
//   cursor @ 0x200000 : int[50000]
//   geoq   @ 0x240000 : ull[50000*24]       (9.6 MB)
//   srcp   @ 0xC00000 : int[50000*24]       (4.8 MB)

__global__ __launch_bounds__(128) void table_kernel(
    const float* __restrict__ W1, const float* __restrict__ W2,
    float* __restrict__ tabP, int* __restrict__ cursor)
{
    int gid = blockIdx.x * 128 + threadIdx.x;
    if (gid < NNODES) cursor[gid] = 0;

    __shared__ float hs[100];
    const int i = blockIdx.x;
    const int t = threadIdx.x;
    const float r = (float)i * (RCUT / (float)(NT - 1));
    if (t < 100) {
        const float step = 2.0f / 9.0f, istep = 4.5f, cemb = 2.8234622f;
        float pre = 0.f;
        #pragma unroll
        for (int j = 0; j < NBASIS; ++j) {
            float dv = (r - (float)j * step) * istep;
            pre += expf(-dv * dv) * cemb * W1[j * 100 + t];
        }
        float z = pre * 0.316227766f;
        hs[t] = z / (1.0f + expf(-z));
    }
    __syncthreads();
    float acc = 0.f;
    for (int k = 0; k < 100; ++k) acc += hs[k] * W2[k * 128 + t];
    float sc = 0.1f * 0.25f;                       // /sqrt(100) * /sqrt(16)
    if (t >= 32 && t < 64) sc *= 1.7320508075688772f;  // sqrt(3) folded for cat-2
    float val = acc * sc;
    if (i < NT - 1) tabP[i * 256 + 2 * t] = val;
    if (i >= 1)     tabP[(i - 1) * 256 + 2 * t + 1] = val;
}

// single pass: activity test + geometry + padded-slot claim
__global__ __launch_bounds__(256) void fill_kernel(
    const float* __restrict__ pos,
    const int* __restrict__ esrc, const int* __restrict__ edst,
    int* __restrict__ cursor,
    unsigned long long* __restrict__ geoq, int* __restrict__ srcp)
{
    int e = blockIdx.x * 256 + threadIdx.x;
    if (e >= NEDGES) return;
    int s = esrc[e], d = edst[e];
    float vx = pos[3*s]   - pos[3*d];
    float vy = pos[3*s+1] - pos[3*d+1];
    float vz = pos[3*s+2] - pos[3*d+2];
    float r2 = vx*vx + vy*vy + vz*vz;
    if (r2 > RCUT * RCUT) return;
    float r = sqrtf(r2 + 1e-12f);
    float inv = 1.0f / r;
    const float iscale = (float)(NT - 1) / RCUT;
    unsigned qx = (unsigned)((vx * inv + 1.0f) * 32767.5f + 0.5f);
    unsigned qy = (unsigned)((vy * inv + 1.0f) * 32767.5f + 0.5f);
    unsigned qz = (unsigned)((vz * inv + 1.0f) * 32767.5f + 0.5f);
    unsigned qf = (unsigned)(r * iscale * 16.0f + 0.5f);
    qx = min(qx, 65535u); qy = min(qy, 65535u); qz = min(qz, 65535u);
    unsigned long long q = (unsigned long long)qx
                         | ((unsigned long long)qy << 16)
                         | ((unsigned long long)qz << 32)
                         | ((unsigned long long)qf << 48);
    int slot = atomicAdd(&cursor[d], 1);
    if (slot < CAP) {
        geoq[(size_t)d * CAP + slot] = q;
        srcp[(size_t)d * CAP + slot] = s;
    }
}

// wave-per-node; R17 depth-2.5 pipeline with sched_barrier(0) fences so the
// compiler cannot sink the early-issued loads to their use point.
__global__ __launch_bounds__(128) void gather_kernel(
    const float* __restrict__ x, const float2* __restrict__ tabP,
    const int* __restrict__ cursor,
    const unsigned long long* __restrict__ geoq, const int* __restrict__ srcp,
    float* __restrict__ out)
{
    const int lane = threadIdx.x & 63;
    const int node = blockIdx.x * 2 + (threadIdx.x >> 6);
    const bool lo = lane < 32;

    // j0: f = lane        -> cat0 (lo) / cat1 (hi)
    const int m0  = lo ? lane : 64 + lane;
    const int xi0 = lo ? lane : 3 * lane - 64;
    // j1: f = 64 + lane   -> cat2, g = lane
    const int uu1 = lane / 3;
    const int m1 = 32 + uu1, xi1 = uu1, c1 = lane - 3 * uu1;
    // j2: f = 128 + lane  -> cat2 (lo) / cat3 (hi)
    const int uu2a = (64 + lane) / 3;
    const int m2  = lo ? 32 + uu2a : 64 + (lane - 32) / 3;
    const int xi2 = lo ? uu2a : lane;
    const int c2  = (64 + lane) - 3 * uu2a;
    // j3: f = 192 + lane  -> cat3, g = 32 + lane
    const int uu3 = (32 + lane) / 3;
    const int m3 = 64 + uu3, xi3 = 64 + lane;

    const int deg = min(cursor[node], CAP);
    const unsigned long long* gq = geoq + (size_t)node * CAP;
    const int* sp = srcp + (size_t)node * CAP;
    float* orow = out + (size_t)node * 256;
    if (deg == 0) {          // wave-uniform
        orow[lane] = 0.f; orow[64 + lane] = 0.f;
        orow[128 + lane] = 0.f; orow[192 + lane] = 0.f;
        return;
    }
    const int degm1 = deg - 1;
    const float DQ = 2.0f / 65535.0f;

    // ---- prologue ----
    unsigned long long qA = gq[0];
    int s0 = sp[0];
    float uxA = (float)((unsigned)(qA       & 0xFFFF)) * DQ - 1.0f;
    float uyA = (float)((unsigned)((qA >> 16) & 0xFFFF)) * DQ - 1.0f;
    float uzA = (float)((unsigned)((qA >> 32) & 0xFFFF)) * DQ - 1.0f;
    float fxA = (float)((unsigned)(qA >> 48)) * 0.0625f;
    int   iiA = min((int)fxA, NT - 2);
    float frA = fxA - (float)iiA;
    const float2* tpA = tabP + (size_t)iiA * 128;
    float2 pA0 = tpA[m0], pA1 = tpA[m1], pA2 = tpA[m2], pA3 = tpA[m3];
    const float* xrA = x + (size_t)s0 * 128;
    float xA0 = xrA[xi0], xA1 = xrA[xi0 + 1], xA2 = xrA[xi0 + 2];
    float xAb = xrA[xi1], xAc = xrA[xi2], xAd = xrA[xi3];

    // edge 1: geo + x loads
    int i1 = min(1, degm1);
    unsigned long long qB = gq[i1];
    int s1 = sp[i1];
    const float* xrB = x + (size_t)s1 * 128;
    float xB0 = xrB[xi0], xB1 = xrB[xi0 + 1], xB2 = xrB[xi0 + 2];
    float xBb = xrB[xi1], xBc = xrB[xi2], xBd = xrB[xi3];

    // edge 2: geo stage C
    int i2 = min(2, degm1);
    unsigned long long qC = gq[i2];
    int sC = sp[i2];

    float a0 = 0.f, a1 = 0.f, a2 = 0.f, a3 = 0.f;

    for (int k = 0; k < deg; ++k) {
        // ---- stage 1: issue far-ahead loads (geo k+3, x k+2) ----
        int i3 = min(k + 3, degm1);
        unsigned long long qD = gq[i3];
        int sD = sp[i3];

        const float* xrC = x + (size_t)sC * 128;
        float xC0 = xrC[xi0], xC1 = xrC[xi0 + 1], xC2 = xrC[xi0 + 2];
        float xCb = xrC[xi1], xCc = xrC[xi2], xCd = xrC[xi3];

        __builtin_amdgcn_sched_barrier(0);   // pin: loads above must issue here

        // ---- stage 2: decode qB + tabP loads for edge k+1 ----
        float uxB = (float)((unsigned)(qB       & 0xFFFF)) * DQ - 1.0f;
        float uyB = (float)((unsigned)((qB >> 16) & 0xFFFF)) * DQ - 1.0f;
        float uzB = (float)((unsigned)((qB >> 32) & 0xFFFF)) * DQ - 1.0f;
        float fxB = (float)((unsigned)(qB >> 48)) * 0.0625f;
        int   iiB = min((int)fxB, NT - 2);
        float frB = fxB - (float)iiB;
        const float2* tpB = tabP + (size_t)iiB * 128;
        float2 pB0 = tpB[m0], pB1 = tpB[m1], pB2 = tpB[m2], pB3 = tpB[m3];

        __builtin_amdgcn_sched_barrier(0);   // pin: tabP issue before compute

        // ---- stage 3: compute edge k from A-state ----
        float w0 = pA0.x + (pA0.y - pA0.x) * frA;
        float w1 = pA1.x + (pA1.y - pA1.x) * frA;
        float w2 = pA2.x + (pA2.y - pA2.x) * frA;
        float w3 = pA3.x + (pA3.y - pA3.x) * frA;
        float u1 = (c1 == 0) ? uxA : (c1 == 1) ? uyA : uzA;
        float u2 = (c2 == 0) ? uxA : (c2 == 1) ? uyA : uzA;
        float dotv = xA0 * uxA + xA1 * uyA + xA2 * uzA;
        a0 += w0 * (lo ? xA0 : dotv);
        a1 += w1 * xAb * u1;
        a2 += w2 * (lo ? xAc * u2 : xAc);
        a3 += w3 * xAd;

        // rotate: B->A (compute state), C->B (x state), D->C (geo state)
        uxA = uxB; uyA = uyB; uzA = uzB; frA = frB;
        pA0 = pB0; pA1 = pB1; pA2 = pB2; pA3 = pB3;
        xA0 = xB0; xA1 = xB1; xA2 = xB2;
        xAb = xBb; xAc = xBc; xAd = xBd;
        xB0 = xC0; xB1 = xC1; xB2 = xC2;
        xBb = xCb; xBc = xCc; xBd = xCd;
        qB = qC;
        sC = sD; qC = qD;
    }

    orow[lane]       = a0;
    orow[64 + lane]  = a1;
    orow[128 + lane] = a2;
    orow[192 + lane] = a3;
}

extern "C" void kernel_launch(void* const* d_in, const int* in_sizes, int n_in,
                              void* d_out, int out_size, void* d_ws, size_t ws_size,
                              hipStream_t stream) {
    const float* pos = (const float*)d_in[0];
    const float* x   = (const float*)d_in[1];
    const float* W1  = (const float*)d_in[2];
    const float* W2  = (const float*)d_in[3];
    const int* esrc  = (const int*)d_in[4];
    const int* edst  = (const int*)d_in[5];
    float* out = (float*)d_out;

    char* wsb = (char*)d_ws;
    float* tabP   = (float*)wsb;
    int* cursor   = (int*)(wsb + 0x200000);
    unsigned long long* geoq = (unsigned long long*)(wsb + 0x240000);
    int* srcp     = (int*)(wsb + 0xC00000);

    table_kernel<<<NT, 128, 0, stream>>>(W1, W2, tabP, cursor);
    fill_kernel<<<(NEDGES + 255) / 256, 256, 0, stream>>>(pos, esrc, edst, cursor, geoq, srcp);
    gather_kernel<<<(NNODES + 1) / 2, 128, 0, stream>>>(x, (const float2*)tabP, cursor, geoq, srcp, out);
}

// Round 19
// 82.542 us; speedup vs baseline: 1.0520x; 1.0520x over previous
//
#include <hip/hip_runtime.h>
#include <math.h>

#define NNODES 50000
#define NEDGES 800000
#define NBASIS 10
#define NT 2048
#define RCUT 3.0f
#define CAP 24          // padded slots/node; P(Poisson(3.6) >= 24) ~ 2e-15

// ws layout (bytes):
//   tabP   @ 0x000000 : float[(NT-1)*256]   (~2 MB, interleaved pair table)
//   cursor @ 0x200000 : int[50000]
//   geoq   @ 0x240000 : ull[50000*24]       (9.6 MB)
//   srcp   @ 0xC00000 : int[50000*24]       (4.8 MB)

__global__ __launch_bounds__(128) void table_kernel(
    const float* __restrict__ W1, const float* __restrict__ W2,
    float* __restrict__ tabP, int* __restrict__ cursor)
{
    int gid = blockIdx.x * 128 + threadIdx.x;
    if (gid < NNODES) cursor[gid] = 0;

    __shared__ float hs[100];
    const int i = blockIdx.x;
    const int t = threadIdx.x;
    const float r = (float)i * (RCUT / (float)(NT - 1));
    if (t < 100) {
        const float step = 2.0f / 9.0f, istep = 4.5f, cemb = 2.8234622f;
        float pre = 0.f;
        #pragma unroll
        for (int j = 0; j < NBASIS; ++j) {
            float dv = (r - (float)j * step) * istep;
            pre += expf(-dv * dv) * cemb * W1[j * 100 + t];
        }
        float z = pre * 0.316227766f;
        hs[t] = z / (1.0f + expf(-z));
    }
    __syncthreads();
    float acc = 0.f;
    for (int k = 0; k < 100; ++k) acc += hs[k] * W2[k * 128 + t];
    float sc = 0.1f * 0.25f;                       // /sqrt(100) * /sqrt(16)
    if (t >= 32 && t < 64) sc *= 1.7320508075688772f;  // sqrt(3) folded for cat-2
    float val = acc * sc;
    if (i < NT - 1) tabP[i * 256 + 2 * t] = val;
    if (i >= 1)     tabP[(i - 1) * 256 + 2 * t + 1] = val;
}

// single pass: activity test + geometry + padded-slot claim
__global__ __launch_bounds__(256) void fill_kernel(
    const float* __restrict__ pos,
    const int* __restrict__ esrc, const int* __restrict__ edst,
    int* __restrict__ cursor,
    unsigned long long* __restrict__ geoq, int* __restrict__ srcp)
{
    int e = blockIdx.x * 256 + threadIdx.x;
    if (e >= NEDGES) return;
    int s = esrc[e], d = edst[e];
    float vx = pos[3*s]   - pos[3*d];
    float vy = pos[3*s+1] - pos[3*d+1];
    float vz = pos[3*s+2] - pos[3*d+2];
    float r2 = vx*vx + vy*vy + vz*vz;
    if (r2 > RCUT * RCUT) return;
    float r = sqrtf(r2 + 1e-12f);
    float inv = 1.0f / r;
    const float iscale = (float)(NT - 1) / RCUT;
    unsigned qx = (unsigned)((vx * inv + 1.0f) * 32767.5f + 0.5f);
    unsigned qy = (unsigned)((vy * inv + 1.0f) * 32767.5f + 0.5f);
    unsigned qz = (unsigned)((vz * inv + 1.0f) * 32767.5f + 0.5f);
    unsigned qf = (unsigned)(r * iscale * 16.0f + 0.5f);
    qx = min(qx, 65535u); qy = min(qy, 65535u); qz = min(qz, 65535u);
    unsigned long long q = (unsigned long long)qx
                         | ((unsigned long long)qy << 16)
                         | ((unsigned long long)qz << 32)
                         | ((unsigned long long)qf << 48);
    int slot = atomicAdd(&cursor[d], 1);
    if (slot < CAP) {
        geoq[(size_t)d * CAP + slot] = q;
        srcp[(size_t)d * CAP + slot] = s;
    }
}

// TWO NODES PER WAVE: lo 32 lanes own node A, hi 32 lanes own node B.
// Two independent edge chains share one instruction stream (2x chains/wave,
// same instruction count per edge). Lane covers 8 features f = p + 32j.
// Inner pipeline = R11's proven placement (issue k+1 loads, compute k, rotate).
__global__ __launch_bounds__(128) void gather_kernel(
    const float* __restrict__ x, const float2* __restrict__ tabP,
    const int* __restrict__ cursor,
    const unsigned long long* __restrict__ geoq, const int* __restrict__ srcp,
    float* __restrict__ out)
{
    const int lane = threadIdx.x & 63;
    const int h    = lane >> 5;                   // which node of the pair
    const int p    = lane & 31;                   // feature slice
    const int node = blockIdx.x * 4 + ((threadIdx.x >> 6) << 1) + h;

    // per-lane feature constants (f = p + 32j), verified in R16:
    const int u2 = p / 3,          c2 = p - 3 * u2;
    const int u3 = (32 + p) / 3,   c3 = (32 + p) - 3 * u3;
    const int u4 = (64 + p) / 3,   c4 = (64 + p) - 3 * u4;
    const int mo0 = p,       mo1 = 96 + p,  mo2 = 32 + u2, mo3 = 32 + u3;
    const int mo4 = 32 + u4, mo5 = 64 + u2, mo6 = 64 + u3, mo7 = 64 + u4;
    const int xo1 = 32 + 3 * p;

    const int deg   = min(cursor[node], CAP);     // uniform within each half
    const int dA    = __shfl(deg, 0, 64);
    const int dB    = __shfl(deg, 32, 64);
    const int maxd  = max(dA, dB);                // wave-uniform loop bound
    const int degm1 = max(deg - 1, 0);
    const size_t gbase = (size_t)node * CAP;
    const float DQ = 2.0f / 65535.0f;

    float a0 = 0.f, a1 = 0.f, a2 = 0.f, a3 = 0.f;
    float a4 = 0.f, a5 = 0.f, a6 = 0.f, a7 = 0.f;

    if (maxd > 0) {
        // ---- prologue: edge-0 state (A), edge-1 geometry (N). Slot 0 may be
        // junk when deg==0 (vf masks it); clamp src into bounds for safety.
        unsigned long long qA = geoq[gbase];
        int sA = min(max(srcp[gbase], 0), NNODES - 1);
        float uxA = (float)((unsigned)(qA       & 0xFFFF)) * DQ - 1.0f;
        float uyA = (float)((unsigned)((qA >> 16) & 0xFFFF)) * DQ - 1.0f;
        float uzA = (float)((unsigned)((qA >> 32) & 0xFFFF)) * DQ - 1.0f;
        float fxA = (float)((unsigned)(qA >> 48)) * 0.0625f;
        int   iiA = min((int)fxA, NT - 2);
        float frA = fxA - (float)iiA;
        const float2* tpA = tabP + (size_t)iiA * 128;
        float2 pA0 = tpA[mo0], pA1 = tpA[mo1], pA2 = tpA[mo2], pA3 = tpA[mo3];
        float2 pA4 = tpA[mo4], pA5 = tpA[mo5], pA6 = tpA[mo6], pA7 = tpA[mo7];
        const float* xrA = x + (size_t)sA * 128;
        float xA0  = xrA[p];
        float xA1a = xrA[xo1], xA1b = xrA[xo1 + 1], xA1c = xrA[xo1 + 2];
        float xA2  = xrA[u2],  xA3  = xrA[u3],      xA4  = xrA[u4];
        float xA5  = xrA[32 + p], xA6 = xrA[64 + p], xA7 = xrA[96 + p];

        unsigned long long qN = geoq[gbase + min(1, degm1)];
        int sN = srcp[gbase + min(1, degm1)];

        for (int k = 0; k < maxd; ++k) {
            // ---- issue edge k+1 loads (B-state), clamped/branchless
            float uxB = (float)((unsigned)(qN       & 0xFFFF)) * DQ - 1.0f;
            float uyB = (float)((unsigned)((qN >> 16) & 0xFFFF)) * DQ - 1.0f;
            float uzB = (float)((unsigned)((qN >> 32) & 0xFFFF)) * DQ - 1.0f;
            float fxB = (float)((unsigned)(qN >> 48)) * 0.0625f;
            int   iiB = min((int)fxB, NT - 2);
            float frB = fxB - (float)iiB;
            const float2* tpB = tabP + (size_t)iiB * 128;
            float2 pB0 = tpB[mo0], pB1 = tpB[mo1], pB2 = tpB[mo2], pB3 = tpB[mo3];
            float2 pB4 = tpB[mo4], pB5 = tpB[mo5], pB6 = tpB[mo6], pB7 = tpB[mo7];
            int sNc = min(max(sN, 0), NNODES - 1);
            const float* xrB = x + (size_t)sNc * 128;
            float xB0  = xrB[p];
            float xB1a = xrB[xo1], xB1b = xrB[xo1 + 1], xB1c = xrB[xo1 + 2];
            float xB2  = xrB[u2],  xB3  = xrB[u3],      xB4  = xrB[u4];
            float xB5  = xrB[32 + p], xB6 = xrB[64 + p], xB7 = xrB[96 + p];
            // geometry prefetch for edge k+2 (clamped)
            int nn = min(k + 2, degm1);
            unsigned long long qNN = geoq[gbase + nn];
            int sNN = srcp[gbase + nn];

            // ---- compute edge k from A-state (masked for the shorter node)
            const float vf = (k < deg) ? 1.0f : 0.0f;
            float w0 = (pA0.x + (pA0.y - pA0.x) * frA) * vf;
            float w1 = (pA1.x + (pA1.y - pA1.x) * frA) * vf;
            float w2 = (pA2.x + (pA2.y - pA2.x) * frA) * vf;
            float w3 = (pA3.x + (pA3.y - pA3.x) * frA) * vf;
            float w4 = (pA4.x + (pA4.y - pA4.x) * frA) * vf;
            float w5 = (pA5.x + (pA5.y - pA5.x) * frA) * vf;
            float w6 = (pA6.x + (pA6.y - pA6.x) * frA) * vf;
            float w7 = (pA7.x + (pA7.y - pA7.x) * frA) * vf;
            float uc2 = (c2 == 0) ? uxA : (c2 == 1) ? uyA : uzA;
            float uc3 = (c3 == 0) ? uxA : (c3 == 1) ? uyA : uzA;
            float uc4 = (c4 == 0) ? uxA : (c4 == 1) ? uyA : uzA;
            a0 += w0 * xA0;
            a1 += w1 * (xA1a * uxA + xA1b * uyA + xA1c * uzA);
            a2 += w2 * xA2 * uc2;
            a3 += w3 * xA3 * uc3;
            a4 += w4 * xA4 * uc4;
            a5 += w5 * xA5;
            a6 += w6 * xA6;
            a7 += w7 * xA7;

            // ---- rotate B -> A, NN -> N
            uxA = uxB; uyA = uyB; uzA = uzB; frA = frB;
            pA0 = pB0; pA1 = pB1; pA2 = pB2; pA3 = pB3;
            pA4 = pB4; pA5 = pB5; pA6 = pB6; pA7 = pB7;
            xA0 = xB0; xA1a = xB1a; xA1b = xB1b; xA1c = xB1c;
            xA2 = xB2; xA3 = xB3; xA4 = xB4;
            xA5 = xB5; xA6 = xB6; xA7 = xB7;
            qN = qNN; sN = sNN;
        }
    }

    // ---- stores: lo half -> node A row, hi half -> node B row (f = p + 32j)
    float* orow = out + (size_t)node * 256;
    orow[p]        = a0;
    orow[32 + p]   = a1;
    orow[64 + p]   = a2;
    orow[96 + p]   = a3;
    orow[128 + p]  = a4;
    orow[160 + p]  = a5;
    orow[192 + p]  = a6;
    orow[224 + p]  = a7;
}

extern "C" void kernel_launch(void* const* d_in, const int* in_sizes, int n_in,
                              void* d_out, int out_size, void* d_ws, size_t ws_size,
                              hipStream_t stream) {
    const float* pos = (const float*)d_in[0];
    const float* x   = (const float*)d_in[1];
    const float* W1  = (const float*)d_in[2];
    const float* W2  = (const float*)d_in[3];
    const int* esrc  = (const int*)d_in[4];
    const int* edst  = (const int*)d_in[5];
    float* out = (float*)d_out;

    char* wsb = (char*)d_ws;
    float* tabP   = (float*)wsb;
    int* cursor   = (int*)(wsb + 0x200000);
    unsigned long long* geoq = (unsigned long long*)(wsb + 0x240000);
    int* srcp     = (int*)(wsb + 0xC00000);

    table_kernel<<<NT, 128, 0, stream>>>(W1, W2, tabP, cursor);
    fill_kernel<<<(NEDGES + 255) / 256, 256, 0, stream>>>(pos, esrc, edst, cursor, geoq, srcp);
    // 4 nodes per 128-thread block (2 waves x 2 nodes)
    gather_kernel<<<NNODES / 4, 128, 0, stream>>>(x, (const float2*)tabP, cursor, geoq, srcp, out);
}

// Round 20
// 75.121 us; speedup vs baseline: 1.1559x; 1.0988x over previous
//
#include <hip/hip_runtime.h>
#include <math.h>

#define NNODES 50000
#define NEDGES 800000
#define NBASIS 10
#define NT 2048
#define RCUT 3.0f
#define CAP 24          // padded slots/node; P(Poisson(3.6) >= 24) ~ 2e-15

// ws layout (bytes):
//   tabP   @ 0x000000 : float[(NT-1)*256]   (~2 MB, interleaved pair table)
//   cursor @ 0x200000 : int[50000]
//   geoq   @ 0x240000 : ull[50000*24]       (9.6 MB)
//   srcp   @ 0xC00000 : int[50000*24]       (4.8 MB)

__global__ __launch_bounds__(128) void table_kernel(
    const float* __restrict__ W1, const float* __restrict__ W2,
    float* __restrict__ tabP, int* __restrict__ cursor)
{
    int gid = blockIdx.x * 128 + threadIdx.x;
    if (gid < NNODES) cursor[gid] = 0;

    __shared__ float hs[100];
    const int i = blockIdx.x;
    const int t = threadIdx.x;
    const float r = (float)i * (RCUT / (float)(NT - 1));
    if (t < 100) {
        const float step = 2.0f / 9.0f, istep = 4.5f, cemb = 2.8234622f;
        float pre = 0.f;
        #pragma unroll
        for (int j = 0; j < NBASIS; ++j) {
            float dv = (r - (float)j * step) * istep;
            pre += expf(-dv * dv) * cemb * W1[j * 100 + t];
        }
        float z = pre * 0.316227766f;
        hs[t] = z / (1.0f + expf(-z));
    }
    __syncthreads();
    float acc = 0.f;
    for (int k = 0; k < 100; ++k) acc += hs[k] * W2[k * 128 + t];
    float sc = 0.1f * 0.25f;                       // /sqrt(100) * /sqrt(16)
    if (t >= 32 && t < 64) sc *= 1.7320508075688772f;  // sqrt(3) folded for cat-2
    float val = acc * sc;
    if (i < NT - 1) tabP[i * 256 + 2 * t] = val;
    if (i >= 1)     tabP[(i - 1) * 256 + 2 * t + 1] = val;
}

// single pass: activity test + geometry + padded-slot claim
__global__ __launch_bounds__(256) void fill_kernel(
    const float* __restrict__ pos,
    const int* __restrict__ esrc, const int* __restrict__ edst,
    int* __restrict__ cursor,
    unsigned long long* __restrict__ geoq, int* __restrict__ srcp)
{
    int e = blockIdx.x * 256 + threadIdx.x;
    if (e >= NEDGES) return;
    int s = esrc[e], d = edst[e];
    float vx = pos[3*s]   - pos[3*d];
    float vy = pos[3*s+1] - pos[3*d+1];
    float vz = pos[3*s+2] - pos[3*d+2];
    float r2 = vx*vx + vy*vy + vz*vz;
    if (r2 > RCUT * RCUT) return;
    float r = sqrtf(r2 + 1e-12f);
    float inv = 1.0f / r;
    const float iscale = (float)(NT - 1) / RCUT;
    unsigned qx = (unsigned)((vx * inv + 1.0f) * 32767.5f + 0.5f);
    unsigned qy = (unsigned)((vy * inv + 1.0f) * 32767.5f + 0.5f);
    unsigned qz = (unsigned)((vz * inv + 1.0f) * 32767.5f + 0.5f);
    unsigned qf = (unsigned)(r * iscale * 16.0f + 0.5f);
    qx = min(qx, 65535u); qy = min(qy, 65535u); qz = min(qz, 65535u);
    unsigned long long q = (unsigned long long)qx
                         | ((unsigned long long)qy << 16)
                         | ((unsigned long long)qz << 32)
                         | ((unsigned long long)qf << 48);
    int slot = atomicAdd(&cursor[d], 1);
    if (slot < CAP) {
        geoq[(size_t)d * CAP + slot] = q;
        srcp[(size_t)d * CAP + slot] = s;
    }
}

// ONE NODE PER 2-WAVE BLOCK, edges split by parity across the waves.
// Each wave runs the R11 pipeline on edges wid, wid+2, ... (identical
// per-edge instruction stream; chain depth halved, chains doubled).
// Partials combined via LDS at the end.
__global__ __launch_bounds__(128) void gather_kernel(
    const float* __restrict__ x, const float2* __restrict__ tabP,
    const int* __restrict__ cursor,
    const unsigned long long* __restrict__ geoq, const int* __restrict__ srcp,
    float* __restrict__ out)
{
    const int lane = threadIdx.x & 63;
    const int wid  = threadIdx.x >> 6;     // edge parity owned by this wave
    const int node = blockIdx.x;
    const bool lo = lane < 32;

    // j0: f = lane        -> cat0 (lo) / cat1 (hi)
    const int m0  = lo ? lane : 64 + lane;
    const int xi0 = lo ? lane : 3 * lane - 64;
    // j1: f = 64 + lane   -> cat2, g = lane
    const int uu1 = lane / 3;
    const int m1 = 32 + uu1, xi1 = uu1, c1 = lane - 3 * uu1;
    // j2: f = 128 + lane  -> cat2 (lo) / cat3 (hi)
    const int uu2a = (64 + lane) / 3;
    const int m2  = lo ? 32 + uu2a : 64 + (lane - 32) / 3;
    const int xi2 = lo ? uu2a : lane;
    const int c2  = (64 + lane) - 3 * uu2a;
    // j3: f = 192 + lane  -> cat3, g = 32 + lane
    const int uu3 = (32 + lane) / 3;
    const int m3 = 64 + uu3, xi3 = 64 + lane;

    const int deg = min(cursor[node], CAP);
    const int nloc = (deg - wid + 1) >> 1;      // edges wid, wid+2, ... < deg
    const size_t gbase = (size_t)node * CAP;
    const int degm1 = (deg > 0) ? deg - 1 : 0;
    const float DQ = 2.0f / 65535.0f;

    __shared__ float part[4][64];

    float a0 = 0.f, a1 = 0.f, a2 = 0.f, a3 = 0.f;

    if (nloc > 0) {
        // ---- prologue: local edge 0 (global edge wid), local edge 1 geometry
        unsigned long long qA = geoq[gbase + wid];
        int sA = srcp[gbase + wid];
        float uxA = (float)((unsigned)(qA       & 0xFFFF)) * DQ - 1.0f;
        float uyA = (float)((unsigned)((qA >> 16) & 0xFFFF)) * DQ - 1.0f;
        float uzA = (float)((unsigned)((qA >> 32) & 0xFFFF)) * DQ - 1.0f;
        float fxA = (float)((unsigned)(qA >> 48)) * 0.0625f;
        int   iiA = min((int)fxA, NT - 2);
        float frA = fxA - (float)iiA;
        const float2* tpA = tabP + (size_t)iiA * 128;
        float2 pA0 = tpA[m0], pA1 = tpA[m1], pA2 = tpA[m2], pA3 = tpA[m3];
        const float* xrA = x + (size_t)sA * 128;
        float xA0 = xrA[xi0], xA1 = xrA[xi0 + 1], xA2 = xrA[xi0 + 2];
        float xAb = xrA[xi1], xAc = xrA[xi2], xAd = xrA[xi3];

        int i1 = min(wid + 2, degm1);
        unsigned long long qN = geoq[gbase + i1];
        int sN = srcp[gbase + i1];

        for (int t = 0; t < nloc; ++t) {
            // decode + issue value loads for local edge t+1 (clamped)
            float uxB = (float)((unsigned)(qN       & 0xFFFF)) * DQ - 1.0f;
            float uyB = (float)((unsigned)((qN >> 16) & 0xFFFF)) * DQ - 1.0f;
            float uzB = (float)((unsigned)((qN >> 32) & 0xFFFF)) * DQ - 1.0f;
            float fxB = (float)((unsigned)(qN >> 48)) * 0.0625f;
            int   iiB = min((int)fxB, NT - 2);
            float frB = fxB - (float)iiB;
            const float2* tpB = tabP + (size_t)iiB * 128;
            float2 pB0 = tpB[m0], pB1 = tpB[m1], pB2 = tpB[m2], pB3 = tpB[m3];
            const float* xrB = x + (size_t)sN * 128;
            float xB0 = xrB[xi0], xB1 = xrB[xi0 + 1], xB2 = xrB[xi0 + 2];
            float xBb = xrB[xi1], xBc = xrB[xi2], xBd = xrB[xi3];
            // geometry prefetch for local edge t+2 (clamped, always valid slot)
            int nn = min(wid + 2 * t + 4, degm1);
            unsigned long long qNN = geoq[gbase + nn];
            int sNN = srcp[gbase + nn];

            // compute local edge t from A-state
            float w0 = pA0.x + (pA0.y - pA0.x) * frA;
            float w1 = pA1.x + (pA1.y - pA1.x) * frA;
            float w2 = pA2.x + (pA2.y - pA2.x) * frA;
            float w3 = pA3.x + (pA3.y - pA3.x) * frA;
            float u1 = (c1 == 0) ? uxA : (c1 == 1) ? uyA : uzA;
            float u2 = (c2 == 0) ? uxA : (c2 == 1) ? uyA : uzA;
            float dotv = xA0 * uxA + xA1 * uyA + xA2 * uzA;
            a0 += w0 * (lo ? xA0 : dotv);
            a1 += w1 * xAb * u1;
            a2 += w2 * (lo ? xAc * u2 : xAc);
            a3 += w3 * xAd;

            // rotate B -> A, NN -> N
            uxA = uxB; uyA = uyB; uzA = uzB; frA = frB;
            pA0 = pB0; pA1 = pB1; pA2 = pB2; pA3 = pB3;
            xA0 = xB0; xA1 = xB1; xA2 = xB2;
            xAb = xBb; xAc = xBc; xAd = xBd;
            qN = qNN; sN = sNN;
        }
    }

    // ---- combine the two waves' partials
    if (wid == 1) {
        part[0][lane] = a0; part[1][lane] = a1;
        part[2][lane] = a2; part[3][lane] = a3;
    }
    __syncthreads();
    if (wid == 0) {
        float* orow = out + (size_t)node * 256;
        orow[lane]       = a0 + part[0][lane];
        orow[64 + lane]  = a1 + part[1][lane];
        orow[128 + lane] = a2 + part[2][lane];
        orow[192 + lane] = a3 + part[3][lane];
    }
}

extern "C" void kernel_launch(void* const* d_in, const int* in_sizes, int n_in,
                              void* d_out, int out_size, void* d_ws, size_t ws_size,
                              hipStream_t stream) {
    const float* pos = (const float*)d_in[0];
    const float* x   = (const float*)d_in[1];
    const float* W1  = (const float*)d_in[2];
    const float* W2  = (const float*)d_in[3];
    const int* esrc  = (const int*)d_in[4];
    const int* edst  = (const int*)d_in[5];
    float* out = (float*)d_out;

    char* wsb = (char*)d_ws;
    float* tabP   = (float*)wsb;
    int* cursor   = (int*)(wsb + 0x200000);
    unsigned long long* geoq = (unsigned long long*)(wsb + 0x240000);
    int* srcp     = (int*)(wsb + 0xC00000);

    table_kernel<<<NT, 128, 0, stream>>>(W1, W2, tabP, cursor);
    fill_kernel<<<(NEDGES + 255) / 256, 256, 0, stream>>>(pos, esrc, edst, cursor, geoq, srcp);
    gather_kernel<<<NNODES, 128, 0, stream>>>(x, (const float2*)tabP, cursor, geoq, srcp, out);
}

// Round 21
// 69.350 us; speedup vs baseline: 1.2521x; 1.0832x over previous
//
#include <hip/hip_runtime.h>
#include <hip/hip_fp16.h>
#include <math.h>

#define NNODES 50000
#define NEDGES 800000
#define NBASIS 10
#define NT 2048
#define RCUT 3.0f
#define CAP 24          // padded slots/node; P(Poisson(3.6) >= 24) ~ 2e-15

// ws layout (bytes):
//   tabPh  @ 0x000000  : half2[(NT-1)*128]   (1 MB, interleaved pair table)
//   cursor @ 0x100000  : int[50000]
//   geoq   @ 0x140000  : ull[50000*24]       (9.6 MB)
//   srcp   @ 0xB00000  : int[50000*24]       (4.8 MB)
//   xh     @ 0x1000000 : half[50000*128]     (12.8 MB)

__global__ __launch_bounds__(128) void table_kernel(
    const float* __restrict__ W1, const float* __restrict__ W2,
    __half* __restrict__ tabh, int* __restrict__ cursor)
{
    int gid = blockIdx.x * 128 + threadIdx.x;
    if (gid < NNODES) cursor[gid] = 0;

    __shared__ float hs[100];
    const int i = blockIdx.x;
    const int t = threadIdx.x;
    const float r = (float)i * (RCUT / (float)(NT - 1));
    if (t < 100) {
        const float step = 2.0f / 9.0f, istep = 4.5f, cemb = 2.8234622f;
        float pre = 0.f;
        #pragma unroll
        for (int j = 0; j < NBASIS; ++j) {
            float dv = (r - (float)j * step) * istep;
            pre += expf(-dv * dv) * cemb * W1[j * 100 + t];
        }
        float z = pre * 0.316227766f;
        hs[t] = z / (1.0f + expf(-z));
    }
    __syncthreads();
    float acc = 0.f;
    for (int k = 0; k < 100; ++k) acc += hs[k] * W2[k * 128 + t];
    float sc = 0.1f * 0.25f;                       // /sqrt(100) * /sqrt(16)
    if (t >= 32 && t < 64) sc *= 1.7320508075688772f;  // sqrt(3) folded for cat-2
    __half hv = __float2half(acc * sc);
    // interleaved pair table: tabh[(i*128+m)*2] = w_i[m]; [..+1] = w_{i+1}[m]
    if (i < NT - 1) tabh[((size_t)i * 128 + t) * 2]           = hv;
    if (i >= 1)     tabh[((size_t)(i - 1) * 128 + t) * 2 + 1] = hv;
}

// single pass: fp16 x-mirror + activity test + geometry + padded-slot claim
__global__ __launch_bounds__(256) void fill_kernel(
    const float* __restrict__ pos, const float* __restrict__ x,
    const int* __restrict__ esrc, const int* __restrict__ edst,
    int* __restrict__ cursor,
    unsigned long long* __restrict__ geoq, int* __restrict__ srcp,
    __half* __restrict__ xh)
{
    int e = blockIdx.x * 256 + threadIdx.x;   // grid exact: 3125*256 = 800000
    // ---- fused x -> fp16 conversion: thread e owns 8 elements (6.4M total)
    {
        const float4 v0 = *(const float4*)(x + (size_t)e * 8);
        const float4 v1 = *(const float4*)(x + (size_t)e * 8 + 4);
        union { __half2 h2[4]; float4 f4; } u;
        u.h2[0] = __floats2half2_rn(v0.x, v0.y);
        u.h2[1] = __floats2half2_rn(v0.z, v0.w);
        u.h2[2] = __floats2half2_rn(v1.x, v1.y);
        u.h2[3] = __floats2half2_rn(v1.z, v1.w);
        *(float4*)(xh + (size_t)e * 8) = u.f4;
    }

    int s = esrc[e], d = edst[e];
    float vx = pos[3*s]   - pos[3*d];
    float vy = pos[3*s+1] - pos[3*d+1];
    float vz = pos[3*s+2] - pos[3*d+2];
    float r2 = vx*vx + vy*vy + vz*vz;
    if (r2 > RCUT * RCUT) return;
    float r = sqrtf(r2 + 1e-12f);
    float inv = 1.0f / r;
    const float iscale = (float)(NT - 1) / RCUT;
    unsigned qx = (unsigned)((vx * inv + 1.0f) * 32767.5f + 0.5f);
    unsigned qy = (unsigned)((vy * inv + 1.0f) * 32767.5f + 0.5f);
    unsigned qz = (unsigned)((vz * inv + 1.0f) * 32767.5f + 0.5f);
    unsigned qf = (unsigned)(r * iscale * 16.0f + 0.5f);
    qx = min(qx, 65535u); qy = min(qy, 65535u); qz = min(qz, 65535u);
    unsigned long long q = (unsigned long long)qx
                         | ((unsigned long long)qy << 16)
                         | ((unsigned long long)qz << 32)
                         | ((unsigned long long)qf << 48);
    int slot = atomicAdd(&cursor[d], 1);
    if (slot < CAP) {
        geoq[(size_t)d * CAP + slot] = q;
        srcp[(size_t)d * CAP + slot] = s;
    }
}

// ONE NODE PER 2-WAVE BLOCK, edges split by parity (R20 structure), with
// fp16 table + fp16 x to halve L1 cache-line traffic per edge.
__global__ __launch_bounds__(128) void gather_kernel(
    const __half* __restrict__ xh, const __half2* __restrict__ tabPh,
    const int* __restrict__ cursor,
    const unsigned long long* __restrict__ geoq, const int* __restrict__ srcp,
    float* __restrict__ out)
{
    const int lane = threadIdx.x & 63;
    const int wid  = threadIdx.x >> 6;     // edge parity owned by this wave
    const int node = blockIdx.x;
    const bool lo = lane < 32;

    // j0: f = lane        -> cat0 (lo) / cat1 (hi)
    const int m0  = lo ? lane : 64 + lane;
    const int xi0 = lo ? lane : 3 * lane - 64;
    // j1: f = 64 + lane   -> cat2, g = lane
    const int uu1 = lane / 3;
    const int m1 = 32 + uu1, xi1 = uu1, c1 = lane - 3 * uu1;
    // j2: f = 128 + lane  -> cat2 (lo) / cat3 (hi)
    const int uu2a = (64 + lane) / 3;
    const int m2  = lo ? 32 + uu2a : 64 + (lane - 32) / 3;
    const int xi2 = lo ? uu2a : lane;
    const int c2  = (64 + lane) - 3 * uu2a;
    // j3: f = 192 + lane  -> cat3, g = 32 + lane
    const int uu3 = (32 + lane) / 3;
    const int m3 = 64 + uu3, xi3 = 64 + lane;

    const int deg = min(cursor[node], CAP);
    const int nloc = (deg - wid + 1) >> 1;      // edges wid, wid+2, ... < deg
    const size_t gbase = (size_t)node * CAP;
    const int degm1 = (deg > 0) ? deg - 1 : 0;
    const float DQ = 2.0f / 65535.0f;

    __shared__ float part[4][64];

    float a0 = 0.f, a1 = 0.f, a2 = 0.f, a3 = 0.f;

    if (nloc > 0) {
        // ---- prologue: local edge 0 (global edge wid), local edge 1 geometry
        unsigned long long qA = geoq[gbase + wid];
        int sA = srcp[gbase + wid];
        float uxA = (float)((unsigned)(qA       & 0xFFFF)) * DQ - 1.0f;
        float uyA = (float)((unsigned)((qA >> 16) & 0xFFFF)) * DQ - 1.0f;
        float uzA = (float)((unsigned)((qA >> 32) & 0xFFFF)) * DQ - 1.0f;
        float fxA = (float)((unsigned)(qA >> 48)) * 0.0625f;
        int   iiA = min((int)fxA, NT - 2);
        float frA = fxA - (float)iiA;
        const __half2* tpA = tabPh + (size_t)iiA * 128;
        __half2 hA0 = tpA[m0], hA1 = tpA[m1], hA2 = tpA[m2], hA3 = tpA[m3];
        const __half* xrA = xh + (size_t)sA * 128;
        float xA0 = __half2float(xrA[xi0]);
        float xA1 = __half2float(xrA[xi0 + 1]);
        float xA2 = __half2float(xrA[xi0 + 2]);
        float xAb = __half2float(xrA[xi1]);
        float xAc = __half2float(xrA[xi2]);
        float xAd = __half2float(xrA[xi3]);

        int i1 = min(wid + 2, degm1);
        unsigned long long qN = geoq[gbase + i1];
        int sN = srcp[gbase + i1];

        for (int t = 0; t < nloc; ++t) {
            // decode + issue value loads for local edge t+1 (clamped)
            float uxB = (float)((unsigned)(qN       & 0xFFFF)) * DQ - 1.0f;
            float uyB = (float)((unsigned)((qN >> 16) & 0xFFFF)) * DQ - 1.0f;
            float uzB = (float)((unsigned)((qN >> 32) & 0xFFFF)) * DQ - 1.0f;
            float fxB = (float)((unsigned)(qN >> 48)) * 0.0625f;
            int   iiB = min((int)fxB, NT - 2);
            float frB = fxB - (float)iiB;
            const __half2* tpB = tabPh + (size_t)iiB * 128;
            __half2 hB0 = tpB[m0], hB1 = tpB[m1], hB2 = tpB[m2], hB3 = tpB[m3];
            const __half* xrB = xh + (size_t)sN * 128;
            float xB0 = __half2float(xrB[xi0]);
            float xB1 = __half2float(xrB[xi0 + 1]);
            float xB2 = __half2float(xrB[xi0 + 2]);
            float xBb = __half2float(xrB[xi1]);
            float xBc = __half2float(xrB[xi2]);
            float xBd = __half2float(xrB[xi3]);
            // geometry prefetch for local edge t+2 (clamped, always valid slot)
            int nn = min(wid + 2 * t + 4, degm1);
            unsigned long long qNN = geoq[gbase + nn];
            int sNN = srcp[gbase + nn];

            // compute local edge t from A-state (fp32 interp)
            float l0 = __low2float(hA0), g0 = __high2float(hA0);
            float l1 = __low2float(hA1), g1 = __high2float(hA1);
            float l2 = __low2float(hA2), g2 = __high2float(hA2);
            float l3 = __low2float(hA3), g3 = __high2float(hA3);
            float w0 = l0 + (g0 - l0) * frA;
            float w1 = l1 + (g1 - l1) * frA;
            float w2 = l2 + (g2 - l2) * frA;
            float w3 = l3 + (g3 - l3) * frA;
            float u1 = (c1 == 0) ? uxA : (c1 == 1) ? uyA : uzA;
            float u2 = (c2 == 0) ? uxA : (c2 == 1) ? uyA : uzA;
            float dotv = xA0 * uxA + xA1 * uyA + xA2 * uzA;
            a0 += w0 * (lo ? xA0 : dotv);
            a1 += w1 * xAb * u1;
            a2 += w2 * (lo ? xAc * u2 : xAc);
            a3 += w3 * xAd;

            // rotate B -> A, NN -> N
            uxA = uxB; uyA = uyB; uzA = uzB; frA = frB;
            hA0 = hB0; hA1 = hB1; hA2 = hB2; hA3 = hB3;
            xA0 = xB0; xA1 = xB1; xA2 = xB2;
            xAb = xBb; xAc = xBc; xAd = xBd;
            qN = qNN; sN = sNN;
        }
    }

    // ---- combine the two waves' partials
    if (wid == 1) {
        part[0][lane] = a0; part[1][lane] = a1;
        part[2][lane] = a2; part[3][lane] = a3;
    }
    __syncthreads();
    if (wid == 0) {
        float* orow = out + (size_t)node * 256;
        orow[lane]       = a0 + part[0][lane];
        orow[64 + lane]  = a1 + part[1][lane];
        orow[128 + lane] = a2 + part[2][lane];
        orow[192 + lane] = a3 + part[3][lane];
    }
}

extern "C" void kernel_launch(void* const* d_in, const int* in_sizes, int n_in,
                              void* d_out, int out_size, void* d_ws, size_t ws_size,
                              hipStream_t stream) {
    const float* pos = (const float*)d_in[0];
    const float* x   = (const float*)d_in[1];
    const float* W1  = (const float*)d_in[2];
    const float* W2  = (const float*)d_in[3];
    const int* esrc  = (const int*)d_in[4];
    const int* edst  = (const int*)d_in[5];
    float* out = (float*)d_out;

    char* wsb = (char*)d_ws;
    __half* tabh  = (__half*)wsb;
    int* cursor   = (int*)(wsb + 0x100000);
    unsigned long long* geoq = (unsigned long long*)(wsb + 0x140000);
    int* srcp     = (int*)(wsb + 0xB00000);
    __half* xh    = (__half*)(wsb + 0x1000000);

    table_kernel<<<NT, 128, 0, stream>>>(W1, W2, tabh, cursor);
    fill_kernel<<<NEDGES / 256, 256, 0, stream>>>(pos, x, esrc, edst, cursor, geoq, srcp, xh);
    gather_kernel<<<NNODES, 128, 0, stream>>>(xh, (const __half2*)tabh, cursor, geoq, srcp, out);
}

// Round 24
// 64.068 us; speedup vs baseline: 1.3554x; 1.0824x over previous
//
#include <hip/hip_runtime.h>
#include <hip/hip_fp16.h>
#include <math.h>

#define NNODES 50000
#define NEDGES 800000
#define NBASIS 10
#define NT 2048
#define RCUT 3.0f
#define CAP 32          // padded slots/node; P(active deg > 32) < 1e-10

// ws layout (bytes):
//   tabPh  @ 0x000000 : half2[(NT-1)*128]  (~1.05 MB, ends 0x0FFE00)
//   cursor @ 0x100000 : int[50000]         (ends 0x130D40)
//   geoq   @ 0x140000 : ull[50000*32]      (12.8 MB, ends 0xD75000)
//   xh     @ 0xD80000 : half[50000*128]    (12.8 MB, ends 0x19B5000)

__global__ __launch_bounds__(128) void table_kernel(
    const float* __restrict__ W1, const float* __restrict__ W2,
    __half* __restrict__ tabh, int* __restrict__ cursor)
{
    int gid = blockIdx.x * 128 + threadIdx.x;
    if (gid < NNODES) cursor[gid] = 0;

    __shared__ float hs[100];
    const int i = blockIdx.x;
    const int t = threadIdx.x;
    const float r = (float)i * (RCUT / (float)(NT - 1));
    if (t < 100) {
        const float step = 2.0f / 9.0f, istep = 4.5f, cemb = 2.8234622f;
        float pre = 0.f;
        #pragma unroll
        for (int j = 0; j < NBASIS; ++j) {
            float dv = (r - (float)j * step) * istep;
            pre += expf(-dv * dv) * cemb * W1[j * 100 + t];
        }
        float z = pre * 0.316227766f;
        hs[t] = z / (1.0f + expf(-z));
    }
    __syncthreads();
    float acc = 0.f;
    for (int k = 0; k < 100; ++k) acc += hs[k] * W2[k * 128 + t];
    float sc = 0.1f * 0.25f;                       // /sqrt(100) * /sqrt(16)
    if (t >= 32 && t < 64) sc *= 1.7320508075688772f;  // sqrt(3) folded for cat-2
    __half hv = __float2half(acc * sc);
    // interleaved pair table: tabh[(i*128+m)*2] = w_i[m]; [..+1] = w_{i+1}[m]
    if (i < NT - 1) tabh[((size_t)i * 128 + t) * 2]           = hv;
    if (i >= 1)     tabh[((size_t)(i - 1) * 128 + t) * 2 + 1] = hv;
}

// single pass: fp16 x-mirror + activity test + packed geometry + slot claim.
// pack: src:16 | fidx*16:15 (<<16) | ux:11 (<<31) | uy:11 (<<42) | uz:11 (<<53)
__global__ __launch_bounds__(256) void fill_kernel(
    const float* __restrict__ pos, const float* __restrict__ x,
    const int* __restrict__ esrc, const int* __restrict__ edst,
    int* __restrict__ cursor, unsigned long long* __restrict__ geoq,
    __half* __restrict__ xh)
{
    int e = blockIdx.x * 256 + threadIdx.x;   // grid exact: 3125*256 = 800000
    // ---- fused x -> fp16 conversion: thread e owns 8 elements (6.4M total)
    {
        const float4 v0 = *(const float4*)(x + (size_t)e * 8);
        const float4 v1 = *(const float4*)(x + (size_t)e * 8 + 4);
        union { __half2 h2[4]; float4 f4; } u;
        u.h2[0] = __floats2half2_rn(v0.x, v0.y);
        u.h2[1] = __floats2half2_rn(v0.z, v0.w);
        u.h2[2] = __floats2half2_rn(v1.x, v1.y);
        u.h2[3] = __floats2half2_rn(v1.z, v1.w);
        *(float4*)(xh + (size_t)e * 8) = u.f4;
    }

    int s = esrc[e], d = edst[e];
    float vx = pos[3*s]   - pos[3*d];
    float vy = pos[3*s+1] - pos[3*d+1];
    float vz = pos[3*s+2] - pos[3*d+2];
    float r2 = vx*vx + vy*vy + vz*vz;
    if (r2 > RCUT * RCUT) return;
    float r = sqrtf(r2 + 1e-12f);
    float inv = 1.0f / r;
    const float iscale = (float)(NT - 1) / RCUT;
    unsigned qf = min((unsigned)(r * iscale * 16.0f + 0.5f), 32767u);
    unsigned ux = min((unsigned)((vx * inv + 1.0f) * 1023.5f + 0.5f), 2047u);
    unsigned uy = min((unsigned)((vy * inv + 1.0f) * 1023.5f + 0.5f), 2047u);
    unsigned uz = min((unsigned)((vz * inv + 1.0f) * 1023.5f + 0.5f), 2047u);
    unsigned long long q = (unsigned long long)(unsigned)s
                         | ((unsigned long long)qf << 16)
                         | ((unsigned long long)ux << 31)
                         | ((unsigned long long)uy << 42)
                         | ((unsigned long long)uz << 53);
    int slot = atomicAdd(&cursor[d], 1);
    if (slot < CAP) geoq[(size_t)d * CAP + slot] = q;
}

// ONE NODE PER 2-WAVE BLOCK, edges split by parity (R20/R21 structure);
// fp16 x + fp16 interp pair-table; src packed in the geo word.
__global__ __launch_bounds__(128) void gather_kernel(
    const __half* __restrict__ xh, const __half2* __restrict__ tabPh,
    const int* __restrict__ cursor, const unsigned long long* __restrict__ geoq,
    float* __restrict__ out)
{
    const int lane = threadIdx.x & 63;
    const int wid  = threadIdx.x >> 6;     // edge parity owned by this wave
    const int node = blockIdx.x;
    const bool lo = lane < 32;

    // j0: f = lane        -> cat0 (lo) / cat1 (hi)
    const int m0  = lo ? lane : 64 + lane;
    const int xi0 = lo ? lane : 3 * lane - 64;
    // j1: f = 64 + lane   -> cat2, g = lane
    const int uu1 = lane / 3;
    const int m1 = 32 + uu1, xi1 = uu1, c1 = lane - 3 * uu1;
    // j2: f = 128 + lane  -> cat2 (lo) / cat3 (hi)
    const int uu2a = (64 + lane) / 3;
    const int m2  = lo ? 32 + uu2a : 64 + (lane - 32) / 3;
    const int xi2 = lo ? uu2a : lane;
    const int c2  = (64 + lane) - 3 * uu2a;
    // j3: f = 192 + lane  -> cat3, g = 32 + lane
    const int uu3 = (32 + lane) / 3;
    const int m3 = 64 + uu3, xi3 = 64 + lane;

    const int deg = min(cursor[node], CAP);
    const int nloc = (deg - wid + 1) >> 1;      // edges wid, wid+2, ... < deg
    const size_t gbase = (size_t)node * CAP;
    const int degm1 = (deg > 0) ? deg - 1 : 0;
    const float DQ = 2.0f / 2047.0f;

    __shared__ float part[4][64];

    float a0 = 0.f, a1 = 0.f, a2 = 0.f, a3 = 0.f;

    if (nloc > 0) {
        // ---- prologue: local edge 0 (global edge wid), local edge 1 geometry
        unsigned long long qA = geoq[gbase + wid];
        int sA = (int)(qA & 0xFFFF);
        float fxA = (float)((unsigned)((qA >> 16) & 0x7FFF)) * 0.0625f;
        float uxA = (float)((unsigned)((qA >> 31) & 0x7FF)) * DQ - 1.0f;
        float uyA = (float)((unsigned)((qA >> 42) & 0x7FF)) * DQ - 1.0f;
        float uzA = (float)((unsigned)(qA >> 53)) * DQ - 1.0f;
        int   iiA = min((int)fxA, NT - 2);
        float frA = fxA - (float)iiA;
        const __half2* tpA = tabPh + (size_t)iiA * 128;
        __half2 hA0 = tpA[m0], hA1 = tpA[m1], hA2 = tpA[m2], hA3 = tpA[m3];
        const __half* xrA = xh + (size_t)sA * 128;
        float xA0 = __half2float(xrA[xi0]);
        float xA1 = __half2float(xrA[xi0 + 1]);
        float xA2 = __half2float(xrA[xi0 + 2]);
        float xAb = __half2float(xrA[xi1]);
        float xAc = __half2float(xrA[xi2]);
        float xAd = __half2float(xrA[xi3]);

        int i1 = min(wid + 2, degm1);
        unsigned long long qN = geoq[gbase + i1];

        for (int t = 0; t < nloc; ++t) {
            // decode + issue value loads for local edge t+1 (clamped)
            int sB = (int)(qN & 0xFFFF);
            float fxB = (float)((unsigned)((qN >> 16) & 0x7FFF)) * 0.0625f;
            float uxB = (float)((unsigned)((qN >> 31) & 0x7FF)) * DQ - 1.0f;
            float uyB = (float)((unsigned)((qN >> 42) & 0x7FF)) * DQ - 1.0f;
            float uzB = (float)((unsigned)(qN >> 53)) * DQ - 1.0f;
            int   iiB = min((int)fxB, NT - 2);
            float frB = fxB - (float)iiB;
            const __half2* tpB = tabPh + (size_t)iiB * 128;
            __half2 hB0 = tpB[m0], hB1 = tpB[m1], hB2 = tpB[m2], hB3 = tpB[m3];
            const __half* xrB = xh + (size_t)sB * 128;
            float xB0 = __half2float(xrB[xi0]);
            float xB1 = __half2float(xrB[xi0 + 1]);
            float xB2 = __half2float(xrB[xi0 + 2]);
            float xBb = __half2float(xrB[xi1]);
            float xBc = __half2float(xrB[xi2]);
            float xBd = __half2float(xrB[xi3]);
            // geometry prefetch for local edge t+2 (clamped, always valid slot)
            int nn = min(wid + 2 * t + 4, degm1);
            unsigned long long qNN = geoq[gbase + nn];

            // compute local edge t from A-state (fp32 interp)
            float l0 = __low2float(hA0), g0 = __high2float(hA0);
            float l1 = __low2float(hA1), g1 = __high2float(hA1);
            float l2 = __low2float(hA2), g2 = __high2float(hA2);
            float l3 = __low2float(hA3), g3 = __high2float(hA3);
            float w0 = l0 + (g0 - l0) * frA;
            float w1 = l1 + (g1 - l1) * frA;
            float w2 = l2 + (g2 - l2) * frA;
            float w3 = l3 + (g3 - l3) * frA;
            float u1 = (c1 == 0) ? uxA : (c1 == 1) ? uyA : uzA;
            float u2 = (c2 == 0) ? uxA : (c2 == 1) ? uyA : uzA;
            float dotv = xA0 * uxA + xA1 * uyA + xA2 * uzA;
            a0 += w0 * (lo ? xA0 : dotv);
            a1 += w1 * xAb * u1;
            a2 += w2 * (lo ? xAc * u2 : xAc);
            a3 += w3 * xAd;

            // rotate B -> A, NN -> N
            uxA = uxB; uyA = uyB; uzA = uzB; frA = frB;
            hA0 = hB0; hA1 = hB1; hA2 = hB2; hA3 = hB3;
            iiA = iiB;
            xA0 = xB0; xA1 = xB1; xA2 = xB2;
            xAb = xBb; xAc = xBc; xAd = xBd;
            qN = qNN;
        }
    }

    // ---- combine the two waves' partials
    if (wid == 1) {
        part[0][lane] = a0; part[1][lane] = a1;
        part[2][lane] = a2; part[3][lane] = a3;
    }
    __syncthreads();
    if (wid == 0) {
        float* orow = out + (size_t)node * 256;
        orow[lane]       = a0 + part[0][lane];
        orow[64 + lane]  = a1 + part[1][lane];
        orow[128 + lane] = a2 + part[2][lane];
        orow[192 + lane] = a3 + part[3][lane];
    }
}

extern "C" void kernel_launch(void* const* d_in, const int* in_sizes, int n_in,
                              void* d_out, int out_size, void* d_ws, size_t ws_size,
                              hipStream_t stream) {
    const float* pos = (const float*)d_in[0];
    const float* x   = (const float*)d_in[1];
    const float* W1  = (const float*)d_in[2];
    const float* W2  = (const float*)d_in[3];
    const int* esrc  = (const int*)d_in[4];
    const int* edst  = (const int*)d_in[5];
    float* out = (float*)d_out;

    char* wsb = (char*)d_ws;
    __half* tabh  = (__half*)wsb;
    int* cursor   = (int*)(wsb + 0x100000);
    unsigned long long* geoq = (unsigned long long*)(wsb + 0x140000);
    __half* xh    = (__half*)(wsb + 0xD80000);

    table_kernel<<<NT, 128, 0, stream>>>(W1, W2, tabh, cursor);
    fill_kernel<<<NEDGES / 256, 256, 0, stream>>>(pos, x, esrc, edst, cursor, geoq, xh);
    gather_kernel<<<NNODES, 128, 0, stream>>>(xh, (const __half2*)tabh, cursor, geoq, out);
}